// Round 10
// baseline (77.582 us; speedup 1.0000x reference)
//
#include <hip/hip_runtime.h>

#define LN_EPS 1e-5f

static constexpr int Hc  = 512;
static constexpr int Fc  = 16;
static constexpr int Sc  = 1024;
static constexpr int RPW = 16;       // rows per wave-pair: same s, consecutive b

// ---- prologue: bsum[h] = sum_i b[i][h] (512 floats into d_ws) ----
__global__ void bsum_kernel(const float* __restrict__ b, float* __restrict__ bsum) {
    int h = blockIdx.x * 64 + threadIdx.x;
    float s = 0.f;
#pragma unroll
    for (int i = 0; i < Fc; ++i) s += b[i * Hc + h];
    bsum[h] = s;
}

// ---- DPP wave64 sum: 6 VALU steps + readlane, no LDS, no barriers ----
template <int CTRL, int RMASK>
__device__ __forceinline__ float dpp_add(float v) {
    int t = __builtin_amdgcn_update_dpp(0, __float_as_int(v), CTRL, RMASK, 0xf, true);
    return v + __int_as_float(t);
}
__device__ __forceinline__ float wave_sum64(float v) {
    v = dpp_add<0x111, 0xf>(v);   // row_shr:1
    v = dpp_add<0x112, 0xf>(v);   // row_shr:2
    v = dpp_add<0x114, 0xf>(v);   // row_shr:4
    v = dpp_add<0x118, 0xf>(v);   // row_shr:8
    v = dpp_add<0x142, 0xa>(v);   // row_bcast:15
    v = dpp_add<0x143, 0xc>(v);   // row_bcast:31 -> lane63 has total
    return __int_as_float(__builtin_amdgcn_readlane(__float_as_int(v), 63));
}

__device__ __forceinline__ float rdlane(float v, int l) {
    return __int_as_float(__builtin_amdgcn_readlane(__float_as_int(v), l));
}

// ---- fused: wave PAIR per (g,s); each wave 256 cols (4 cols/lane) ----
// W panel 64 VGPR -> total ~110 VGPR -> 4 waves/SIMD (2x R9 occupancy).
// Zero VMEM loads in the loop (emb[s]+bsum loop-invariant, x gathered up front).
// LN stats cross the pair via LDS + raw s_barrier (lgkmcnt-only wait: stores
// must stay in flight -- __syncthreads would drain vmcnt and serialize on them).
__global__ __launch_bounds__(256) void fused_kernel(
    const float* __restrict__ x, const float* __restrict__ W,
    const float* __restrict__ emb, const float* __restrict__ bsum,
    const float* __restrict__ gamma, const float* __restrict__ beta,
    float* __restrict__ out)
{
    __shared__ float2 part[2][4];   // [row parity][wave]

    const int lane  = threadIdx.x & 63;
    const int wv    = threadIdx.x >> 6;        // 0..3
    const int half  = wv & 1;                  // which 256-col half
    const int p     = blockIdx.x * 2 + (wv >> 1);   // pair id 0..8191
    const int s     = p & (Sc - 1);
    const int g     = p >> 10;                 // 0..7 (b-group)
    const int h     = half * 256 + lane * 4;

    // register-resident W panel: 16 K-rows x 4 cols per lane (64 VGPR)
    float4 Wp[Fc];
#pragma unroll
    for (int i = 0; i < Fc; ++i)
        Wp[i] = *reinterpret_cast<const float4*>(&W[i * Hc + h]);

    // x for all 16 rows up front: 4 gather loads; xq[q] lane l holds
    // x[b = g*16 + q*4 + (l>>4)][s][l&15]  (4 x 64B segments per instr)
    const int sub = lane >> 4, i16 = lane & 15;
    float xq0, xq1, xq2, xq3;
    {
        const size_t xoff = (size_t)s * Fc + i16;
        xq0 = __builtin_nontemporal_load(&x[(size_t)(g * 16 +  0 + sub) * Sc * Fc + xoff]);
        xq1 = __builtin_nontemporal_load(&x[(size_t)(g * 16 +  4 + sub) * Sc * Fc + xoff]);
        xq2 = __builtin_nontemporal_load(&x[(size_t)(g * 16 +  8 + sub) * Sc * Fc + xoff]);
        xq3 = __builtin_nontemporal_load(&x[(size_t)(g * 16 + 12 + sub) * Sc * Fc + xoff]);
    }

    // loop-invariant per-wave vectors
    const float4 gmv = *reinterpret_cast<const float4*>(&gamma[h]);
    const float4 bev = *reinterpret_cast<const float4*>(&beta[h]);
    float4 ebs;
    {
        const float4 e  = *reinterpret_cast<const float4*>(&emb[(size_t)s * Hc + h]);
        const float4 bs = *reinterpret_cast<const float4*>(&bsum[h]);
        ebs.x = e.x + bs.x; ebs.y = e.y + bs.y; ebs.z = e.z + bs.z; ebs.w = e.w + bs.w;
    }

#pragma unroll
    for (int t = 0; t < RPW; ++t) {
        const float xsrc = (t >> 2) == 0 ? xq0 : (t >> 2) == 1 ? xq1 : (t >> 2) == 2 ? xq2 : xq3;
        float xs[Fc];
#pragma unroll
        for (int i = 0; i < Fc; ++i)
            xs[i] = rdlane(xsrc, (t & 3) * 16 + i);

        // pure-register FMA chain (64 fma/row/wave)
        float4 a = ebs;
#pragma unroll
        for (int i = 0; i < Fc; ++i) {
            a.x = fmaf(xs[i], Wp[i].x, a.x);
            a.y = fmaf(xs[i], Wp[i].y, a.y);
            a.z = fmaf(xs[i], Wp[i].z, a.z);
            a.w = fmaf(xs[i], Wp[i].w, a.w);
        }

        float psum = a.x + a.y + a.z + a.w;
        float pssq = fmaf(a.x, a.x, fmaf(a.y, a.y, fmaf(a.z, a.z, a.w * a.w)));

        float sum = wave_sum64(psum);   // sum over this wave's 256 cols
        float ssq = wave_sum64(pssq);

        // exchange half-row stats with partner wave (wv^1); one barrier/row,
        // parity ping-pong makes write@t+2 safe vs read@t.
        if (lane == 0) part[t & 1][wv] = make_float2(sum, ssq);
        asm volatile("s_waitcnt lgkmcnt(0)" ::: "memory");
        __builtin_amdgcn_s_barrier();
        asm volatile("" ::: "memory");
        const float2 o = part[t & 1][wv ^ 1];
        sum += o.x; ssq += o.y;

        const float mean = sum * (1.0f / 512.0f);
        const float var  = ssq * (1.0f / 512.0f) - mean * mean;
        const float rs   = rsqrtf(var + LN_EPS);

        float4 r;
        r.x = (a.x - mean) * rs * gmv.x + bev.x;
        r.y = (a.y - mean) * rs * gmv.y + bev.y;
        r.z = (a.z - mean) * rs * gmv.z + bev.z;
        r.w = (a.w - mean) * rs * gmv.w + bev.w;
        *reinterpret_cast<float4*>(&out[((size_t)(g * 16 + t) * Sc + s) * Hc + h]) = r;
    }
}

extern "C" void kernel_launch(void* const* d_in, const int* in_sizes, int n_in,
                              void* d_out, int out_size, void* d_ws, size_t ws_size,
                              hipStream_t stream) {
    const float* x     = (const float*)d_in[0];
    const float* W     = (const float*)d_in[1];
    const float* b     = (const float*)d_in[2];
    const float* emb   = (const float*)d_in[3];
    const float* gamma = (const float*)d_in[4];
    const float* beta  = (const float*)d_in[5];
    float* out  = (float*)d_out;
    float* bsum = (float*)d_ws;     // 512 floats

    bsum_kernel<<<Hc / 64, 64, 0, stream>>>(b, bsum);

    const int blocks = (8 * Sc) / 2;   // 16384 waves = 8192 pairs; 2 pairs/block
    fused_kernel<<<blocks, 256, 0, stream>>>(x, W, emb, bsum, gamma, beta, out);
}